// Round 1
// baseline (636.145 us; speedup 1.0000x reference)
//
#include <hip/hip_runtime.h>
#include <hip/hip_bf16.h>

#define LRELU(t) ((t) > 0.0f ? (t) : 0.01f * (t))

// ---------- GEMM: C[M x 128] = A[M x 128] @ B[128 x 128] + bias ----------
// Tile: 64 rows x 128 cols, K in 2 chunks of 64. LDS ~48KB -> 3 blocks/CU.
__global__ __launch_bounds__(256) void gemm128_kernel(
    const float* __restrict__ A, int lda, const float* __restrict__ B,
    const float* __restrict__ bias, float* __restrict__ C, int ldo, int M) {
  __shared__ float Ws[64 * 128];
  __shared__ float Xs[64 * 64];
  const int t = threadIdx.x;
  const int row0 = blockIdx.x * 64;
  const int c0 = (t & 31) * 4;
  const int r0 = (t >> 5) * 8;
  float acc[8][4];
#pragma unroll
  for (int i = 0; i < 8; ++i)
#pragma unroll
    for (int j = 0; j < 4; ++j) acc[i][j] = 0.f;

  for (int kc = 0; kc < 2; ++kc) {
    const int k0 = kc * 64;
    // stage W chunk: rows k0..k0+63 of B, contiguous 2048 float4
#pragma unroll
    for (int i = 0; i < 8; ++i) {
      int f = t + i * 256;
      float4 w4 = *reinterpret_cast<const float4*>(B + (size_t)k0 * 128 + f * 4);
      *reinterpret_cast<float4*>(&Ws[f * 4]) = w4;
    }
    // stage X chunk: 64 rows x 64 k
#pragma unroll
    for (int i = 0; i < 4; ++i) {
      int f = t + i * 256;
      int r = f >> 4, kq = f & 15;
      float4 x4 = make_float4(0.f, 0.f, 0.f, 0.f);
      int row = row0 + r;
      if (row < M) x4 = *reinterpret_cast<const float4*>(A + (size_t)row * lda + k0 + kq * 4);
      *reinterpret_cast<float4*>(&Xs[r * 64 + kq * 4]) = x4;
    }
    __syncthreads();
#pragma unroll 8
    for (int kk = 0; kk < 64; ++kk) {
      float4 b4 = *reinterpret_cast<const float4*>(&Ws[kk * 128 + c0]);
#pragma unroll
      for (int i = 0; i < 8; ++i) {
        float av = Xs[(r0 + i) * 64 + kk];
        acc[i][0] += av * b4.x;
        acc[i][1] += av * b4.y;
        acc[i][2] += av * b4.z;
        acc[i][3] += av * b4.w;
      }
    }
    __syncthreads();
  }
  float4 bs = make_float4(0.f, 0.f, 0.f, 0.f);
  if (bias) bs = *reinterpret_cast<const float4*>(bias + c0);
#pragma unroll
  for (int i = 0; i < 8; ++i) {
    int row = row0 + r0 + i;
    if (row < M) {
      float4 o;
      o.x = acc[i][0] + bs.x;
      o.y = acc[i][1] + bs.y;
      o.z = acc[i][2] + bs.z;
      o.w = acc[i][3] + bs.w;
      *reinterpret_cast<float4*>(C + (size_t)row * ldo + c0) = o;
    }
  }
}

// ---------- zero ----------
__global__ void zero_kernel(int* __restrict__ p, int n) {
  int i = blockIdx.x * blockDim.x + threadIdx.x;
  if (i < n) p[i] = 0;
}

// ---------- histogram of col ----------
__global__ void count_kernel(const int* __restrict__ col, int* __restrict__ counts, int E) {
  int e = blockIdx.x * blockDim.x + threadIdx.x;
  if (e < E) atomicAdd(&counts[col[e]], 1);
}

// ---------- 3-kernel exclusive scan over N1 = N+1 elements ----------
__global__ __launch_bounds__(1024) void scan1_kernel(const int* __restrict__ counts,
                                                     int* __restrict__ offsets,
                                                     int* __restrict__ bsum, int N, int N1) {
  __shared__ int sh[1024];
  int tid = threadIdx.x;
  int i = blockIdx.x * 1024 + tid;
  int v = (i < N) ? counts[i] : 0;
  sh[tid] = v;
  __syncthreads();
  for (int off = 1; off < 1024; off <<= 1) {
    int tv = (tid >= off) ? sh[tid - off] : 0;
    __syncthreads();
    sh[tid] += tv;
    __syncthreads();
  }
  if (i < N1) offsets[i] = sh[tid] - v;  // exclusive within block
  if (tid == 1023) bsum[blockIdx.x] = sh[1023];
}

__global__ __launch_bounds__(128) void scan2_kernel(int* __restrict__ bsum, int NB) {
  __shared__ int sh[128];
  int tid = threadIdx.x;
  int v = (tid < NB) ? bsum[tid] : 0;
  sh[tid] = v;
  __syncthreads();
  for (int off = 1; off < 128; off <<= 1) {
    int tv = (tid >= off) ? sh[tid - off] : 0;
    __syncthreads();
    sh[tid] += tv;
    __syncthreads();
  }
  if (tid < NB) bsum[tid] = sh[tid] - v;  // exclusive
}

__global__ __launch_bounds__(1024) void scan3_kernel(int* __restrict__ offsets,
                                                     const int* __restrict__ bsum,
                                                     int* __restrict__ cursor, int N, int N1) {
  int i = blockIdx.x * 1024 + threadIdx.x;
  if (i < N1) {
    int o = offsets[i] + bsum[blockIdx.x];
    offsets[i] = o;
    if (i < N) cursor[i] = o;
  }
}

// ---------- self-loop attention score (constant): leaky(ba1)@Wa2 + ba2 ----------
__global__ __launch_bounds__(64) void prep_kernel(const float* __restrict__ ba1,
                                                  const float* __restrict__ Wa2,
                                                  const float* __restrict__ ba2,
                                                  float* __restrict__ a_self) {
  int l = threadIdx.x;
  float t1 = ba1[l], t2 = ba1[l + 64];
  float v = LRELU(t1) * Wa2[l] + LRELU(t2) * Wa2[l + 64];
#pragma unroll
  for (int off = 32; off > 0; off >>= 1) v += __shfl_xor(v, off);
  if (l == 0) *a_self = v + ba2[0];
}

// ---------- scatter edges into CSR (by col) ----------
__global__ void scatter_kernel(const int* __restrict__ col, int* __restrict__ cursor,
                               int* __restrict__ csr, int E) {
  int e = blockIdx.x * blockDim.x + threadIdx.x;
  if (e < E) {
    int pos = atomicAdd(&cursor[col[e]], 1);
    csr[pos] = e;
  }
}

// ---------- per-edge attention logit: one wave per edge ----------
// a_e = leaky(P[rol]-P[col]+ba1) . Wa2 + ba2   where P part lives at embP[row*256+128..]
__global__ __launch_bounds__(256) void edge_a_kernel(
    const int* __restrict__ rol, const int* __restrict__ col,
    const float* __restrict__ embP, const float* __restrict__ ba1,
    const float* __restrict__ Wa2, const float* __restrict__ ba2,
    float* __restrict__ a_out, int E) {
  int wid = threadIdx.x >> 6, lane = threadIdx.x & 63;
  int e = blockIdx.x * 4 + wid;
  if (e >= E) return;
  int r = rol[e], c = col[e];
  const float* Pr = embP + (size_t)r * 256 + 128;
  const float* Pc = embP + (size_t)c * 256 + 128;
  float t1 = Pr[lane] - Pc[lane] + ba1[lane];
  float t2 = Pr[lane + 64] - Pc[lane + 64] + ba1[lane + 64];
  float v = LRELU(t1) * Wa2[lane] + LRELU(t2) * Wa2[lane + 64];
#pragma unroll
  for (int off = 32; off > 0; off >>= 1) v += __shfl_xor(v, off);
  if (lane == 0) a_out[e] = v + ba2[0];
}

// ---------- per-node segment softmax + aggregation: one block (128 thr) per node ----------
__global__ __launch_bounds__(128) void node_kernel(
    const int* __restrict__ offsets, const int* __restrict__ csr,
    const int* __restrict__ rol, const float* __restrict__ a_arr,
    const float* __restrict__ a_self_p, const float* __restrict__ embP,
    float* __restrict__ msg) {
  int n = blockIdx.x;
  int c = threadIdx.x;
  int j0 = offsets[n], j1 = offsets[n + 1];
  float a_self = *a_self_p;
  float m = a_self;
  for (int j = j0; j < j1; ++j) m = fmaxf(m, a_arr[csr[j]]);
  float s = expf(a_self - m);                       // self-loop weight
  float acc = s * embP[(size_t)n * 256 + c];        // emb part at offset 0
  for (int j = j0; j < j1; ++j) {
    int e = csr[j];
    float be = expf(a_arr[e] - m);
    s += be;
    acc += be * embP[(size_t)rol[e] * 256 + c];
  }
  msg[(size_t)n * 128 + c] = acc / (s + 1e-16f);
}

extern "C" void kernel_launch(void* const* d_in, const int* in_sizes, int n_in,
                              void* d_out, int out_size, void* d_ws, size_t ws_size,
                              hipStream_t stream) {
  const float* x     = (const float*)d_in[0];
  const int*   ei    = (const int*)d_in[1];
  const float* W_emb = (const float*)d_in[2];
  const float* b_emb = (const float*)d_in[3];
  const float* Wa1   = (const float*)d_in[4];
  const float* ba1   = (const float*)d_in[5];
  const float* Wa2   = (const float*)d_in[6];
  const float* ba2   = (const float*)d_in[7];
  const float* W_upd = (const float*)d_in[8];
  const float* b_upd = (const float*)d_in[9];
  float* out = (float*)d_out;

  const int N = in_sizes[0] / 128;
  const int E = in_sizes[1] / 2;
  const int* rol = ei;
  const int* col = ei + E;

  // workspace layout (~160 MB)
  float* embP   = (float*)d_ws;                 // N*256  [emb(128) | P=x@Wa1(128)]
  float* msg    = embP + (size_t)N * 256;       // N*128
  float* a_arr  = msg + (size_t)N * 128;        // E
  float* a_self = a_arr + E;                    // 1
  int* counts   = (int*)(a_self + 1);           // N
  int* offsets  = counts + N;                   // N+1
  int* cursor   = offsets + N + 1;              // N
  int* csr      = cursor + N;                   // E
  int* bsum     = csr + E;                      // NB

  const int N1 = N + 1;
  const int NB = (N1 + 1023) / 1024;  // 98 for N=100000 (must be <=128)
  const int mtiles = (N + 63) / 64;

  zero_kernel<<<(N + 255) / 256, 256, 0, stream>>>(counts, N);

  // embP = [x@W_emb + b_emb | x@Wa1]   (ba1 added per-edge; it cancels in P[rol]-P[col])
  gemm128_kernel<<<mtiles, 256, 0, stream>>>(x, 128, W_emb, b_emb, embP, 256, N);
  gemm128_kernel<<<mtiles, 256, 0, stream>>>(x, 128, Wa1, nullptr, embP + 128, 256, N);

  count_kernel<<<(E + 255) / 256, 256, 0, stream>>>(col, counts, E);
  scan1_kernel<<<NB, 1024, 0, stream>>>(counts, offsets, bsum, N, N1);
  scan2_kernel<<<1, 128, 0, stream>>>(bsum, NB);
  scan3_kernel<<<NB, 1024, 0, stream>>>(offsets, bsum, cursor, N, N1);
  prep_kernel<<<1, 64, 0, stream>>>(ba1, Wa2, ba2, a_self);
  scatter_kernel<<<(E + 255) / 256, 256, 0, stream>>>(col, cursor, csr, E);

  edge_a_kernel<<<(E + 3) / 4, 256, 0, stream>>>(rol, col, embP, ba1, Wa2, ba2, a_arr, E);
  node_kernel<<<N, 128, 0, stream>>>(offsets, csr, rol, a_arr, a_self, embP, msg);

  gemm128_kernel<<<mtiles, 256, 0, stream>>>(msg, 128, W_upd, b_upd, out, 128, N);
}

// Round 3
// 460.580 us; speedup vs baseline: 1.3812x; 1.3812x over previous
//
#include <hip/hip_runtime.h>
#include <hip/hip_bf16.h>

#define LRELU(t) ((t) > 0.0f ? (t) : 0.01f * (t))

__device__ __forceinline__ unsigned short f2bf(float f) {
  unsigned u = __float_as_uint(f);
  u += 0x7fff + ((u >> 16) & 1);  // round-to-nearest-even
  return (unsigned short)(u >> 16);
}
__device__ __forceinline__ float bflo(unsigned u) { return __uint_as_float(u << 16); }
__device__ __forceinline__ float bfhi(unsigned u) { return __uint_as_float(u & 0xffff0000u); }

// ---------- GEMM: C[M x 128] = A[M x 128] @ B[128 x 128] + bias ----------
// Tile: 64 rows x 128 cols, K in 2 chunks of 64. Optional bf16 output.
template <bool BF16OUT>
__global__ __launch_bounds__(256) void gemm128_kernel(
    const float* __restrict__ A, int lda, const float* __restrict__ B,
    const float* __restrict__ bias, void* __restrict__ Cout, int ldo, int M) {
  __shared__ float Ws[64 * 128];
  __shared__ float Xs[64 * 64];
  const int t = threadIdx.x;
  const int row0 = blockIdx.x * 64;
  const int c0 = (t & 31) * 4;
  const int r0 = (t >> 5) * 8;
  float acc[8][4];
#pragma unroll
  for (int i = 0; i < 8; ++i)
#pragma unroll
    for (int j = 0; j < 4; ++j) acc[i][j] = 0.f;

  for (int kc = 0; kc < 2; ++kc) {
    const int k0 = kc * 64;
#pragma unroll
    for (int i = 0; i < 8; ++i) {
      int f = t + i * 256;
      float4 w4 = *reinterpret_cast<const float4*>(B + (size_t)k0 * 128 + f * 4);
      *reinterpret_cast<float4*>(&Ws[f * 4]) = w4;
    }
#pragma unroll
    for (int i = 0; i < 4; ++i) {
      int f = t + i * 256;
      int r = f >> 4, kq = f & 15;
      float4 x4 = make_float4(0.f, 0.f, 0.f, 0.f);
      int row = row0 + r;
      if (row < M) x4 = *reinterpret_cast<const float4*>(A + (size_t)row * lda + k0 + kq * 4);
      *reinterpret_cast<float4*>(&Xs[r * 64 + kq * 4]) = x4;
    }
    __syncthreads();
#pragma unroll 8
    for (int kk = 0; kk < 64; ++kk) {
      float4 b4 = *reinterpret_cast<const float4*>(&Ws[kk * 128 + c0]);
#pragma unroll
      for (int i = 0; i < 8; ++i) {
        float av = Xs[(r0 + i) * 64 + kk];
        acc[i][0] += av * b4.x;
        acc[i][1] += av * b4.y;
        acc[i][2] += av * b4.z;
        acc[i][3] += av * b4.w;
      }
    }
    __syncthreads();
  }
  float4 bs = make_float4(0.f, 0.f, 0.f, 0.f);
  if (bias) bs = *reinterpret_cast<const float4*>(bias + c0);
#pragma unroll
  for (int i = 0; i < 8; ++i) {
    int row = row0 + r0 + i;
    if (row < M) {
      float vx = acc[i][0] + bs.x, vy = acc[i][1] + bs.y;
      float vz = acc[i][2] + bs.z, vw = acc[i][3] + bs.w;
      if (BF16OUT) {
        ushort4 o;
        o.x = f2bf(vx); o.y = f2bf(vy); o.z = f2bf(vz); o.w = f2bf(vw);
        *reinterpret_cast<ushort4*>((unsigned short*)Cout + (size_t)row * ldo + c0) = o;
      } else {
        float4 o = make_float4(vx, vy, vz, vw);
        *reinterpret_cast<float4*>((float*)Cout + (size_t)row * ldo + c0) = o;
      }
    }
  }
}

// ---------- zero ----------
__global__ void zero_kernel(int* __restrict__ p, int n) {
  int i = blockIdx.x * blockDim.x + threadIdx.x;
  if (i < n) p[i] = 0;
}

// ---------- histogram of col ----------
__global__ void count_kernel(const int* __restrict__ col, int* __restrict__ counts, int E) {
  int e = blockIdx.x * blockDim.x + threadIdx.x;
  if (e < E) atomicAdd(&counts[col[e]], 1);
}

// ---------- 3-kernel exclusive scan over N1 = N+1 elements ----------
__global__ __launch_bounds__(1024) void scan1_kernel(const int* __restrict__ counts,
                                                     int* __restrict__ offsets,
                                                     int* __restrict__ bsum, int N, int N1) {
  __shared__ int sh[1024];
  int tid = threadIdx.x;
  int i = blockIdx.x * 1024 + tid;
  int v = (i < N) ? counts[i] : 0;
  sh[tid] = v;
  __syncthreads();
  for (int off = 1; off < 1024; off <<= 1) {
    int tv = (tid >= off) ? sh[tid - off] : 0;
    __syncthreads();
    sh[tid] += tv;
    __syncthreads();
  }
  if (i < N1) offsets[i] = sh[tid] - v;
  if (tid == 1023) bsum[blockIdx.x] = sh[1023];
}

__global__ __launch_bounds__(128) void scan2_kernel(int* __restrict__ bsum, int NB) {
  __shared__ int sh[128];
  int tid = threadIdx.x;
  int v = (tid < NB) ? bsum[tid] : 0;
  sh[tid] = v;
  __syncthreads();
  for (int off = 1; off < 128; off <<= 1) {
    int tv = (tid >= off) ? sh[tid - off] : 0;
    __syncthreads();
    sh[tid] += tv;
    __syncthreads();
  }
  if (tid < NB) bsum[tid] = sh[tid] - v;
}

__global__ __launch_bounds__(1024) void scan3_kernel(int* __restrict__ offsets,
                                                     const int* __restrict__ bsum,
                                                     int* __restrict__ cursor, int N, int N1) {
  int i = blockIdx.x * 1024 + threadIdx.x;
  if (i < N1) {
    int o = offsets[i] + bsum[blockIdx.x];
    offsets[i] = o;
    if (i < N) cursor[i] = o;
  }
}

// ---------- self-loop attention score (constant): leaky(ba1)@Wa2 + ba2 ----------
__global__ __launch_bounds__(64) void prep_kernel(const float* __restrict__ ba1,
                                                  const float* __restrict__ Wa2,
                                                  const float* __restrict__ ba2,
                                                  float* __restrict__ a_self) {
  int l = threadIdx.x;
  float t1 = ba1[l], t2 = ba1[l + 64];
  float v = LRELU(t1) * Wa2[l] + LRELU(t2) * Wa2[l + 64];
#pragma unroll
  for (int off = 32; off > 0; off >>= 1) v += __shfl_xor(v, off);
  if (l == 0) *a_self = v + ba2[0];
}

// ---------- fused edge logit + CSR scatter: 2 edges per wave, grid-stride ----------
__global__ __launch_bounds__(256) void edge_kernel(
    const int* __restrict__ rol, const int* __restrict__ col,
    const unsigned* __restrict__ Pu,  // P as bf16 pairs, N x 64 u32
    const float2* __restrict__ ba1_2, const float2* __restrict__ Wa2_2,
    const float* __restrict__ ba2, int* __restrict__ cursor,
    float* __restrict__ a_csr, int* __restrict__ rol_csr, int E, int nwt) {
  const int lane = threadIdx.x & 63;
  const int wid = blockIdx.x * (blockDim.x >> 6) + (threadIdx.x >> 6);
  const float2 b2 = ba1_2[lane];
  const float2 w2 = Wa2_2[lane];
  const float ba2v = *ba2;
  const int npairs = (E + 1) >> 1;
  for (int p = wid; p < npairs; p += nwt) {
    int e0 = 2 * p, e1 = 2 * p + 1;
    bool has1 = e1 < E;
    int r0 = rol[e0], c0 = col[e0];
    int r1 = has1 ? rol[e1] : r0;
    int c1 = has1 ? col[e1] : c0;
    unsigned pr0 = Pu[(size_t)r0 * 64 + lane];
    unsigned pc0 = Pu[(size_t)c0 * 64 + lane];
    unsigned pr1 = Pu[(size_t)r1 * 64 + lane];
    unsigned pc1 = Pu[(size_t)c1 * 64 + lane];
    float t00 = bflo(pr0) - bflo(pc0) + b2.x;
    float t01 = bfhi(pr0) - bfhi(pc0) + b2.y;
    float v0 = LRELU(t00) * w2.x + LRELU(t01) * w2.y;
    float t10 = bflo(pr1) - bflo(pc1) + b2.x;
    float t11 = bfhi(pr1) - bfhi(pc1) + b2.y;
    float v1 = LRELU(t10) * w2.x + LRELU(t11) * w2.y;
#pragma unroll
    for (int off = 32; off > 0; off >>= 1) {
      v0 += __shfl_xor(v0, off);
      v1 += __shfl_xor(v1, off);
    }
    if (lane == 0) {
      int pos0 = atomicAdd(&cursor[c0], 1);
      a_csr[pos0] = v0 + ba2v;
      rol_csr[pos0] = r0;
      if (has1) {
        int pos1 = atomicAdd(&cursor[c1], 1);
        a_csr[pos1] = v1 + ba2v;
        rol_csr[pos1] = r1;
      }
    }
  }
}

// ---------- per-node softmax over contiguous a_csr -> normalized weights ----------
__global__ void softmax_kernel(const int* __restrict__ offsets, const float* __restrict__ a_csr,
                               const float* __restrict__ a_self_p, float* __restrict__ w_csr,
                               float* __restrict__ w_self, int N) {
  int n = blockIdx.x * blockDim.x + threadIdx.x;
  if (n >= N) return;
  int j0 = offsets[n], j1 = offsets[n + 1];
  float a_self = *a_self_p;
  float m = a_self;
  for (int j = j0; j < j1; ++j) m = fmaxf(m, a_csr[j]);
  float es = expf(a_self - m);
  float s = es;
  for (int j = j0; j < j1; ++j) {
    float e = expf(a_csr[j] - m);
    w_csr[j] = e;
    s += e;
  }
  float inv = 1.0f / (s + 1e-16f);
  w_self[n] = es * inv;
  for (int j = j0; j < j1; ++j) w_csr[j] *= inv;
}

// ---------- aggregation: one wave per node, float2 cols/lane, unroll 4 ----------
__global__ __launch_bounds__(256) void agg_kernel(
    const int* __restrict__ offsets, const int* __restrict__ rol_csr,
    const float* __restrict__ w_csr, const float* __restrict__ w_self,
    const unsigned* __restrict__ Eu,  // emb as bf16 pairs, N x 64 u32
    float* __restrict__ msg, int N, int nwt) {
  const int lane = threadIdx.x & 63;
  const int wid = blockIdx.x * (blockDim.x >> 6) + (threadIdx.x >> 6);
  for (int n = wid; n < N; n += nwt) {
    int j0 = offsets[n], j1 = offsets[n + 1];
    float ws = w_self[n];
    unsigned us = Eu[(size_t)n * 64 + lane];
    float accx = ws * bflo(us), accy = ws * bfhi(us);
    int j = j0;
    for (; j + 4 <= j1; j += 4) {
      int r0 = rol_csr[j], r1 = rol_csr[j + 1], r2 = rol_csr[j + 2], r3 = rol_csr[j + 3];
      float w0 = w_csr[j], w1 = w_csr[j + 1], w2 = w_csr[j + 2], w3 = w_csr[j + 3];
      unsigned u0 = Eu[(size_t)r0 * 64 + lane];
      unsigned u1 = Eu[(size_t)r1 * 64 + lane];
      unsigned u2 = Eu[(size_t)r2 * 64 + lane];
      unsigned u3 = Eu[(size_t)r3 * 64 + lane];
      accx += w0 * bflo(u0) + w1 * bflo(u1) + w2 * bflo(u2) + w3 * bflo(u3);
      accy += w0 * bfhi(u0) + w1 * bfhi(u1) + w2 * bfhi(u2) + w3 * bfhi(u3);
    }
    for (; j < j1; ++j) {
      int r = rol_csr[j];
      float w = w_csr[j];
      unsigned u = Eu[(size_t)r * 64 + lane];
      accx += w * bflo(u);
      accy += w * bfhi(u);
    }
    *reinterpret_cast<float2*>(msg + (size_t)n * 128 + lane * 2) = make_float2(accx, accy);
  }
}

extern "C" void kernel_launch(void* const* d_in, const int* in_sizes, int n_in,
                              void* d_out, int out_size, void* d_ws, size_t ws_size,
                              hipStream_t stream) {
  const float* x     = (const float*)d_in[0];
  const int*   ei    = (const int*)d_in[1];
  const float* W_emb = (const float*)d_in[2];
  const float* b_emb = (const float*)d_in[3];
  const float* Wa1   = (const float*)d_in[4];
  const float* ba1   = (const float*)d_in[5];
  const float* Wa2   = (const float*)d_in[6];
  const float* ba2   = (const float*)d_in[7];
  const float* W_upd = (const float*)d_in[8];
  const float* b_upd = (const float*)d_in[9];
  float* out = (float*)d_out;

  const int N = in_sizes[0] / 128;
  const int E = in_sizes[1] / 2;
  const int* rol = ei;
  const int* col = ei + E;

  // workspace carve (all 256B aligned)
  char* base = (char*)d_ws;
  size_t off = 0;
  auto carve = [&](size_t bytes) {
    void* p = base + off;
    off = (off + bytes + 255) & ~(size_t)255;
    return p;
  };
  unsigned* emb_u  = (unsigned*)carve((size_t)N * 64 * 4);  // emb bf16 pairs
  unsigned* P_u    = (unsigned*)carve((size_t)N * 64 * 4);  // P bf16 pairs
  float*    msg    = (float*)carve((size_t)N * 128 * 4);
  float*    a_csr  = (float*)carve((size_t)E * 4);
  float*    w_csr  = (float*)carve((size_t)E * 4);
  int*      rol_csr= (int*)carve((size_t)E * 4);
  float*    w_self = (float*)carve((size_t)N * 4);
  float*    a_self = (float*)carve(16);
  int*      counts = (int*)carve((size_t)N * 4);
  int*      offsets= (int*)carve((size_t)(N + 1) * 4);
  int*      cursor = (int*)carve((size_t)N * 4);
  int*      bsum   = (int*)carve(128 * 4);
  (void)ws_size;

  const int N1 = N + 1;
  const int NB = (N1 + 1023) / 1024;  // 98 for N=100000 (must be <=128)
  const int mtiles = (N + 63) / 64;
  const int SBLK = 2048;               // grid-stride blocks (8192 waves)
  const int NWT = SBLK * 4;

  zero_kernel<<<(N + 255) / 256, 256, 0, stream>>>(counts, N);

  gemm128_kernel<true><<<mtiles, 256, 0, stream>>>(x, 128, W_emb, b_emb, emb_u, 128, N);
  gemm128_kernel<true><<<mtiles, 256, 0, stream>>>(x, 128, Wa1, nullptr, P_u, 128, N);

  count_kernel<<<(E + 255) / 256, 256, 0, stream>>>(col, counts, E);
  scan1_kernel<<<NB, 1024, 0, stream>>>(counts, offsets, bsum, N, N1);
  scan2_kernel<<<1, 128, 0, stream>>>(bsum, NB);
  scan3_kernel<<<NB, 1024, 0, stream>>>(offsets, bsum, cursor, N, N1);
  prep_kernel<<<1, 64, 0, stream>>>(ba1, Wa2, ba2, a_self);

  edge_kernel<<<SBLK, 256, 0, stream>>>(rol, col, P_u, (const float2*)ba1, (const float2*)Wa2,
                                        ba2, cursor, a_csr, rol_csr, E, NWT);
  softmax_kernel<<<(N + 255) / 256, 256, 0, stream>>>(offsets, a_csr, a_self, w_csr, w_self, N);
  agg_kernel<<<SBLK, 256, 0, stream>>>(offsets, rol_csr, w_csr, w_self, emb_u, msg, N, NWT);

  gemm128_kernel<false><<<mtiles, 256, 0, stream>>>(msg, 128, W_upd, b_upd, out, 128, N);
}

// Round 4
// 406.300 us; speedup vs baseline: 1.5657x; 1.1336x over previous
//
#include <hip/hip_runtime.h>
#include <hip/hip_bf16.h>

#define LRELU(t) ((t) > 0.0f ? (t) : 0.01f * (t))

__device__ __forceinline__ unsigned short f2bf(float f) {
  unsigned u = __float_as_uint(f);
  u += 0x7fff + ((u >> 16) & 1);  // round-to-nearest-even
  return (unsigned short)(u >> 16);
}
__device__ __forceinline__ float bflo(unsigned u) { return __uint_as_float(u << 16); }
__device__ __forceinline__ float bfhi(unsigned u) { return __uint_as_float(u & 0xffff0000u); }

// ---------- GEMM: C[M x 128] = A[M x 128] @ B[128 x 128] + bias ----------
// Tile: 64 rows x 128 cols, K in 2 chunks of 64. Optional bf16 output (ldo in ushort units).
template <bool BF16OUT>
__global__ __launch_bounds__(256) void gemm128_kernel(
    const float* __restrict__ A, int lda, const float* __restrict__ B,
    const float* __restrict__ bias, void* __restrict__ Cout, int ldo, int M) {
  __shared__ float Ws[64 * 128];
  __shared__ float Xs[64 * 64];
  const int t = threadIdx.x;
  const int row0 = blockIdx.x * 64;
  const int c0 = (t & 31) * 4;
  const int r0 = (t >> 5) * 8;
  float acc[8][4];
#pragma unroll
  for (int i = 0; i < 8; ++i)
#pragma unroll
    for (int j = 0; j < 4; ++j) acc[i][j] = 0.f;

  for (int kc = 0; kc < 2; ++kc) {
    const int k0 = kc * 64;
#pragma unroll
    for (int i = 0; i < 8; ++i) {
      int f = t + i * 256;
      float4 w4 = *reinterpret_cast<const float4*>(B + (size_t)k0 * 128 + f * 4);
      *reinterpret_cast<float4*>(&Ws[f * 4]) = w4;
    }
#pragma unroll
    for (int i = 0; i < 4; ++i) {
      int f = t + i * 256;
      int r = f >> 4, kq = f & 15;
      float4 x4 = make_float4(0.f, 0.f, 0.f, 0.f);
      int row = row0 + r;
      if (row < M) x4 = *reinterpret_cast<const float4*>(A + (size_t)row * lda + k0 + kq * 4);
      *reinterpret_cast<float4*>(&Xs[r * 64 + kq * 4]) = x4;
    }
    __syncthreads();
#pragma unroll 8
    for (int kk = 0; kk < 64; ++kk) {
      float4 b4 = *reinterpret_cast<const float4*>(&Ws[kk * 128 + c0]);
#pragma unroll
      for (int i = 0; i < 8; ++i) {
        float av = Xs[(r0 + i) * 64 + kk];
        acc[i][0] += av * b4.x;
        acc[i][1] += av * b4.y;
        acc[i][2] += av * b4.z;
        acc[i][3] += av * b4.w;
      }
    }
    __syncthreads();
  }
  float4 bs = make_float4(0.f, 0.f, 0.f, 0.f);
  if (bias) bs = *reinterpret_cast<const float4*>(bias + c0);
#pragma unroll
  for (int i = 0; i < 8; ++i) {
    int row = row0 + r0 + i;
    if (row < M) {
      float vx = acc[i][0] + bs.x, vy = acc[i][1] + bs.y;
      float vz = acc[i][2] + bs.z, vw = acc[i][3] + bs.w;
      if (BF16OUT) {
        ushort4 o;
        o.x = f2bf(vx); o.y = f2bf(vy); o.z = f2bf(vz); o.w = f2bf(vw);
        *reinterpret_cast<ushort4*>((unsigned short*)Cout + (size_t)row * ldo + c0) = o;
      } else {
        float4 o = make_float4(vx, vy, vz, vw);
        *reinterpret_cast<float4*>((float*)Cout + (size_t)row * ldo + c0) = o;
      }
    }
  }
}

// ---------- zero ----------
__global__ void zero_kernel(int* __restrict__ p, int n) {
  int i = blockIdx.x * blockDim.x + threadIdx.x;
  if (i < n) p[i] = 0;
}

// ---------- histogram of col ----------
__global__ void count_kernel(const int* __restrict__ col, int* __restrict__ counts, int E) {
  int e = blockIdx.x * blockDim.x + threadIdx.x;
  if (e < E) atomicAdd(&counts[col[e]], 1);
}

// ---------- 3-kernel exclusive scan over N1 = N+1 elements ----------
__global__ __launch_bounds__(1024) void scan1_kernel(const int* __restrict__ counts,
                                                     int* __restrict__ offsets,
                                                     int* __restrict__ bsum, int N, int N1) {
  __shared__ int sh[1024];
  int tid = threadIdx.x;
  int i = blockIdx.x * 1024 + tid;
  int v = (i < N) ? counts[i] : 0;
  sh[tid] = v;
  __syncthreads();
  for (int off = 1; off < 1024; off <<= 1) {
    int tv = (tid >= off) ? sh[tid - off] : 0;
    __syncthreads();
    sh[tid] += tv;
    __syncthreads();
  }
  if (i < N1) offsets[i] = sh[tid] - v;
  if (tid == 1023) bsum[blockIdx.x] = sh[1023];
}

__global__ __launch_bounds__(128) void scan2_kernel(int* __restrict__ bsum, int NB) {
  __shared__ int sh[128];
  int tid = threadIdx.x;
  int v = (tid < NB) ? bsum[tid] : 0;
  sh[tid] = v;
  __syncthreads();
  for (int off = 1; off < 128; off <<= 1) {
    int tv = (tid >= off) ? sh[tid - off] : 0;
    __syncthreads();
    sh[tid] += tv;
    __syncthreads();
  }
  if (tid < NB) bsum[tid] = sh[tid] - v;
}

__global__ __launch_bounds__(1024) void scan3_kernel(int* __restrict__ offsets,
                                                     const int* __restrict__ bsum,
                                                     int* __restrict__ cursor, int N, int N1) {
  int i = blockIdx.x * 1024 + threadIdx.x;
  if (i < N1) {
    int o = offsets[i] + bsum[blockIdx.x];
    offsets[i] = o;
    if (i < N) cursor[i] = o;
  }
}

// ---------- self-loop attention score (constant): leaky(ba1)@Wa2 + ba2 ----------
__global__ __launch_bounds__(64) void prep_kernel(const float* __restrict__ ba1,
                                                  const float* __restrict__ Wa2,
                                                  const float* __restrict__ ba2,
                                                  float* __restrict__ a_self) {
  int l = threadIdx.x;
  float t1 = ba1[l], t2 = ba1[l + 64];
  float v = LRELU(t1) * Wa2[l] + LRELU(t2) * Wa2[l + 64];
#pragma unroll
  for (int off = 32; off > 0; off >>= 1) v += __shfl_xor(v, off);
  if (l == 0) *a_self = v + ba2[0];
}

// ---------- CSR build: scatter rol values grouped by col ----------
__global__ void scatter_kernel(const int* __restrict__ rol, const int* __restrict__ col,
                               int* __restrict__ cursor, int* __restrict__ csr_rol, int E) {
  int e = blockIdx.x * blockDim.x + threadIdx.x;
  if (e < E) {
    int pos = atomicAdd(&cursor[col[e]], 1);
    csr_rol[pos] = rol[e];
  }
}

// ---------- fused flash-style node kernel: one wave per node, online softmax ----------
// embP row layout (u32 pairs): [0..63] = emb bf16x2, [64..127] = P bf16x2  (512 B/row)
__global__ __launch_bounds__(256) void fused_kernel(
    const int* __restrict__ offsets, const int* __restrict__ csr_rol,
    const unsigned* __restrict__ embP, const float2* __restrict__ ba1_2,
    const float2* __restrict__ Wa2_2, const float* __restrict__ ba2,
    const float* __restrict__ a_self_p, float* __restrict__ msg, int N, int nwt) {
  const int lane = threadIdx.x & 63;
  const int wid = blockIdx.x * (blockDim.x >> 6) + (threadIdx.x >> 6);
  const float2 b2 = ba1_2[lane];
  const float2 w2 = Wa2_2[lane];
  const float ba2v = *ba2;
  const float aself = *a_self_p;

#define LOGIT(pp) (LRELU(bflo(pp) - pcx + b2.x) * w2.x + LRELU(bfhi(pp) - pcy + b2.y) * w2.y)
#define ONLINE(aval, ue)                      \
  {                                           \
    float nm = fmaxf(m, (aval));              \
    float cc = __expf(m - nm);                \
    float w = __expf((aval)-nm);              \
    s = s * cc + w;                           \
    ax = ax * cc + w * bflo(ue);              \
    ay = ay * cc + w * bfhi(ue);              \
    m = nm;                                   \
  }

  for (int n = wid; n < N; n += nwt) {
    int j0 = offsets[n], j1 = offsets[n + 1];
    unsigned ue_own = embP[(size_t)n * 128 + lane];
    unsigned up_own = embP[(size_t)n * 128 + 64 + lane];
    float pcx = bflo(up_own), pcy = bfhi(up_own);
    // init with self-loop: m = a_self, weight exp(0)=1
    float m = aself, s = 1.0f;
    float ax = bflo(ue_own), ay = bfhi(ue_own);
    int j = j0;
    for (; j + 4 <= j1; j += 4) {
      int r0 = csr_rol[j], r1 = csr_rol[j + 1], r2 = csr_rol[j + 2], r3 = csr_rol[j + 3];
      unsigned pe0 = embP[(size_t)r0 * 128 + lane];
      unsigned pp0 = embP[(size_t)r0 * 128 + 64 + lane];
      unsigned pe1 = embP[(size_t)r1 * 128 + lane];
      unsigned pp1 = embP[(size_t)r1 * 128 + 64 + lane];
      unsigned pe2 = embP[(size_t)r2 * 128 + lane];
      unsigned pp2 = embP[(size_t)r2 * 128 + 64 + lane];
      unsigned pe3 = embP[(size_t)r3 * 128 + lane];
      unsigned pp3 = embP[(size_t)r3 * 128 + 64 + lane];
      float v0 = LOGIT(pp0), v1 = LOGIT(pp1), v2 = LOGIT(pp2), v3 = LOGIT(pp3);
#pragma unroll
      for (int off = 32; off > 0; off >>= 1) {
        v0 += __shfl_xor(v0, off);
        v1 += __shfl_xor(v1, off);
        v2 += __shfl_xor(v2, off);
        v3 += __shfl_xor(v3, off);
      }
      ONLINE(v0 + ba2v, pe0);
      ONLINE(v1 + ba2v, pe1);
      ONLINE(v2 + ba2v, pe2);
      ONLINE(v3 + ba2v, pe3);
    }
    for (; j < j1; ++j) {
      int r = csr_rol[j];
      unsigned pe = embP[(size_t)r * 128 + lane];
      unsigned pp = embP[(size_t)r * 128 + 64 + lane];
      float v = LOGIT(pp);
#pragma unroll
      for (int off = 32; off > 0; off >>= 1) v += __shfl_xor(v, off);
      ONLINE(v + ba2v, pe);
    }
    float inv = 1.0f / (s + 1e-16f);
    *reinterpret_cast<float2*>(msg + (size_t)n * 128 + lane * 2) =
        make_float2(ax * inv, ay * inv);
  }
#undef LOGIT
#undef ONLINE
}

extern "C" void kernel_launch(void* const* d_in, const int* in_sizes, int n_in,
                              void* d_out, int out_size, void* d_ws, size_t ws_size,
                              hipStream_t stream) {
  const float* x     = (const float*)d_in[0];
  const int*   ei    = (const int*)d_in[1];
  const float* W_emb = (const float*)d_in[2];
  const float* b_emb = (const float*)d_in[3];
  const float* Wa1   = (const float*)d_in[4];
  const float* ba1   = (const float*)d_in[5];
  const float* Wa2   = (const float*)d_in[6];
  const float* ba2   = (const float*)d_in[7];
  const float* W_upd = (const float*)d_in[8];
  const float* b_upd = (const float*)d_in[9];
  float* out = (float*)d_out;

  const int N = in_sizes[0] / 128;
  const int E = in_sizes[1] / 2;
  const int* rol = ei;
  const int* col = ei + E;

  // workspace carve (all 256B aligned)
  char* base = (char*)d_ws;
  size_t off = 0;
  auto carve = [&](size_t bytes) {
    void* p = base + off;
    off = (off + bytes + 255) & ~(size_t)255;
    return p;
  };
  unsigned* embP   = (unsigned*)carve((size_t)N * 128 * 4);  // [emb|P] bf16 pairs, 512B/row
  float*    msg    = (float*)carve((size_t)N * 128 * 4);
  int*      csr_rol= (int*)carve((size_t)E * 4);
  float*    a_self = (float*)carve(16);
  int*      counts = (int*)carve((size_t)N * 4);
  int*      offsets= (int*)carve((size_t)(N + 1) * 4);
  int*      cursor = (int*)carve((size_t)N * 4);
  int*      bsum   = (int*)carve(128 * 4);
  (void)ws_size;

  const int N1 = N + 1;
  const int NB = (N1 + 1023) / 1024;  // 98 for N=100000 (must be <=128)
  const int mtiles = (N + 63) / 64;
  const int SBLK = 2048;              // grid-stride blocks (8192 waves)
  const int NWT = SBLK * 4;

  zero_kernel<<<(N + 255) / 256, 256, 0, stream>>>(counts, N);

  // embP = [x@W_emb + b_emb | x@Wa1] as bf16, interleaved per row (ldo in ushorts = 256)
  gemm128_kernel<true><<<mtiles, 256, 0, stream>>>(x, 128, W_emb, b_emb, embP, 256, N);
  gemm128_kernel<true><<<mtiles, 256, 0, stream>>>(x, 128, Wa1, nullptr,
                                                   (unsigned short*)embP + 128, 256, N);

  count_kernel<<<(E + 255) / 256, 256, 0, stream>>>(col, counts, E);
  scan1_kernel<<<NB, 1024, 0, stream>>>(counts, offsets, bsum, N, N1);
  scan2_kernel<<<1, 128, 0, stream>>>(bsum, NB);
  scan3_kernel<<<NB, 1024, 0, stream>>>(offsets, bsum, cursor, N, N1);
  prep_kernel<<<1, 64, 0, stream>>>(ba1, Wa2, ba2, a_self);
  scatter_kernel<<<(E + 255) / 256, 256, 0, stream>>>(rol, col, cursor, csr_rol, E);

  fused_kernel<<<SBLK, 256, 0, stream>>>(offsets, csr_rol, embP, (const float2*)ba1,
                                         (const float2*)Wa2, ba2, a_self, msg, N, NWT);

  gemm128_kernel<false><<<mtiles, 256, 0, stream>>>(msg, 128, W_upd, b_upd, out, 128, N);
}

// Round 5
// 346.441 us; speedup vs baseline: 1.8362x; 1.1728x over previous
//
#include <hip/hip_runtime.h>
#include <hip/hip_bf16.h>

#define LRELU(t) ((t) > 0.0f ? (t) : 0.01f * (t))

typedef __attribute__((ext_vector_type(8))) short bf16x8;
typedef __attribute__((ext_vector_type(4))) float f32x4;

__device__ __forceinline__ unsigned short f2bf(float f) {
  unsigned u = __float_as_uint(f);
  u += 0x7fff + ((u >> 16) & 1);  // round-to-nearest-even
  return (unsigned short)(u >> 16);
}
__device__ __forceinline__ float bflo(unsigned u) { return __uint_as_float(u << 16); }
__device__ __forceinline__ float bfhi(unsigned u) { return __uint_as_float(u & 0xffff0000u); }

// ---------- weight transpose + bf16 convert (one-shot, tiny) ----------
// WtA[256][128] = [W_emb^T ; Wa1^T],  WtU[128][128] = W_upd^T
__global__ __launch_bounds__(256) void wtrans_kernel(
    const float* __restrict__ W_emb, const float* __restrict__ Wa1,
    const float* __restrict__ W_upd, unsigned short* __restrict__ WtA,
    unsigned short* __restrict__ WtU) {
  int i = blockIdx.x * 256 + threadIdx.x;
  if (i < 32768) {
    int n = i >> 7, k = i & 127;
    float v = (n < 128) ? W_emb[k * 128 + n] : Wa1[k * 128 + (n - 128)];
    WtA[i] = f2bf(v);
  } else if (i < 49152) {
    int j = i - 32768;
    int n = j >> 7, k = j & 127;
    WtU[j] = f2bf(W_upd[k * 128 + n]);
  }
}

// ---------- MFMA GEMM 1+2 fused: embP[M x 256](bf16) = bf16(x[M x128]) @ [W_emb|Wa1] ----------
// bias b_emb on cols 0..127 only. Block = 4 waves, tile 64 rows x 256 cols (wave w: cols w*64).
// A fragments loaded directly from global f32 (wave collectively coalesced), B from Wt (bf16, L2-hot).
__global__ __launch_bounds__(256) void gemm_embP_kernel(
    const float* __restrict__ A, const unsigned short* __restrict__ Wt,
    const float* __restrict__ b_emb, unsigned short* __restrict__ C, int M) {
  const int lane = threadIdx.x & 63;
  const int w = threadIdx.x >> 6;
  const int row0 = blockIdx.x * 64;
  const int ncol0 = w * 64;
  const int lr = lane & 15;
  const int lg = lane >> 4;
  f32x4 acc[4][4];
#pragma unroll
  for (int mf = 0; mf < 4; ++mf)
#pragma unroll
    for (int nf = 0; nf < 4; ++nf) acc[mf][nf] = (f32x4){0.f, 0.f, 0.f, 0.f};

#pragma unroll
  for (int ks = 0; ks < 4; ++ks) {
    const int k0 = ks * 32 + lg * 8;
    bf16x8 bfr[4];
#pragma unroll
    for (int nf = 0; nf < 4; ++nf)
      bfr[nf] = *reinterpret_cast<const bf16x8*>(Wt + (size_t)(ncol0 + nf * 16 + lr) * 128 + k0);
    bf16x8 afr[4];
#pragma unroll
    for (int mf = 0; mf < 4; ++mf) {
      int row = row0 + mf * 16 + lr;
      if (row >= M) row = M - 1;
      const float* ap = A + (size_t)row * 128 + k0;
      float4 a0 = *reinterpret_cast<const float4*>(ap);
      float4 a1 = *reinterpret_cast<const float4*>(ap + 4);
      bf16x8 t;
      t[0] = (short)f2bf(a0.x); t[1] = (short)f2bf(a0.y);
      t[2] = (short)f2bf(a0.z); t[3] = (short)f2bf(a0.w);
      t[4] = (short)f2bf(a1.x); t[5] = (short)f2bf(a1.y);
      t[6] = (short)f2bf(a1.z); t[7] = (short)f2bf(a1.w);
      afr[mf] = t;
    }
#pragma unroll
    for (int mf = 0; mf < 4; ++mf)
#pragma unroll
      for (int nf = 0; nf < 4; ++nf)
        acc[mf][nf] =
            __builtin_amdgcn_mfma_f32_16x16x32_bf16(afr[mf], bfr[nf], acc[mf][nf], 0, 0, 0);
  }
#pragma unroll
  for (int nf = 0; nf < 4; ++nf) {
    int col = ncol0 + nf * 16 + lr;
    float bv = (col < 128) ? b_emb[col] : 0.0f;
#pragma unroll
    for (int mf = 0; mf < 4; ++mf) {
      int rowb = row0 + mf * 16 + lg * 4;
#pragma unroll
      for (int r = 0; r < 4; ++r) {
        int row = rowb + r;
        if (row < M) C[(size_t)row * 256 + col] = f2bf(acc[mf][nf][r] + bv);
      }
    }
  }
}

// ---------- MFMA GEMM 3: out[M x 128](f32) = msg_bf16[M x128] @ W_upd + b_upd ----------
// Block = 4 waves, tile 128 rows x 128 cols (wave w: rows (w>>1)*64, cols (w&1)*64).
__global__ __launch_bounds__(256) void gemm_out_kernel(
    const unsigned short* __restrict__ Ab, const unsigned short* __restrict__ Wt,
    const float* __restrict__ b_upd, float* __restrict__ Cout, int M) {
  const int lane = threadIdx.x & 63;
  const int w = threadIdx.x >> 6;
  const int row0 = blockIdx.x * 128 + (w >> 1) * 64;
  const int ncol0 = (w & 1) * 64;
  const int lr = lane & 15;
  const int lg = lane >> 4;
  f32x4 acc[4][4];
#pragma unroll
  for (int mf = 0; mf < 4; ++mf)
#pragma unroll
    for (int nf = 0; nf < 4; ++nf) acc[mf][nf] = (f32x4){0.f, 0.f, 0.f, 0.f};

#pragma unroll
  for (int ks = 0; ks < 4; ++ks) {
    const int k0 = ks * 32 + lg * 8;
    bf16x8 bfr[4];
#pragma unroll
    for (int nf = 0; nf < 4; ++nf)
      bfr[nf] = *reinterpret_cast<const bf16x8*>(Wt + (size_t)(ncol0 + nf * 16 + lr) * 128 + k0);
    bf16x8 afr[4];
#pragma unroll
    for (int mf = 0; mf < 4; ++mf) {
      int row = row0 + mf * 16 + lr;
      if (row >= M) row = M - 1;
      afr[mf] = *reinterpret_cast<const bf16x8*>(Ab + (size_t)row * 128 + k0);
    }
#pragma unroll
    for (int mf = 0; mf < 4; ++mf)
#pragma unroll
      for (int nf = 0; nf < 4; ++nf)
        acc[mf][nf] =
            __builtin_amdgcn_mfma_f32_16x16x32_bf16(afr[mf], bfr[nf], acc[mf][nf], 0, 0, 0);
  }
#pragma unroll
  for (int nf = 0; nf < 4; ++nf) {
    int col = ncol0 + nf * 16 + lr;
    float bv = b_upd[col];
#pragma unroll
    for (int mf = 0; mf < 4; ++mf) {
      int rowb = row0 + mf * 16 + lg * 4;
#pragma unroll
      for (int r = 0; r < 4; ++r) {
        int row = rowb + r;
        if (row < M) Cout[(size_t)row * 128 + col] = acc[mf][nf][r] + bv;
      }
    }
  }
}

// ---------- zero ----------
__global__ void zero_kernel(int* __restrict__ p, int n) {
  int i = blockIdx.x * blockDim.x + threadIdx.x;
  if (i < n) p[i] = 0;
}

// ---------- histogram of col ----------
__global__ void count_kernel(const int* __restrict__ col, int* __restrict__ counts, int E) {
  int e = blockIdx.x * blockDim.x + threadIdx.x;
  if (e < E) atomicAdd(&counts[col[e]], 1);
}

// ---------- 3-kernel exclusive scan over N1 = N+1 elements ----------
__global__ __launch_bounds__(1024) void scan1_kernel(const int* __restrict__ counts,
                                                     int* __restrict__ offsets,
                                                     int* __restrict__ bsum, int N, int N1) {
  __shared__ int sh[1024];
  int tid = threadIdx.x;
  int i = blockIdx.x * 1024 + tid;
  int v = (i < N) ? counts[i] : 0;
  sh[tid] = v;
  __syncthreads();
  for (int off = 1; off < 1024; off <<= 1) {
    int tv = (tid >= off) ? sh[tid - off] : 0;
    __syncthreads();
    sh[tid] += tv;
    __syncthreads();
  }
  if (i < N1) offsets[i] = sh[tid] - v;
  if (tid == 1023) bsum[blockIdx.x] = sh[1023];
}

__global__ __launch_bounds__(128) void scan2_kernel(int* __restrict__ bsum, int NB) {
  __shared__ int sh[128];
  int tid = threadIdx.x;
  int v = (tid < NB) ? bsum[tid] : 0;
  sh[tid] = v;
  __syncthreads();
  for (int off = 1; off < 128; off <<= 1) {
    int tv = (tid >= off) ? sh[tid - off] : 0;
    __syncthreads();
    sh[tid] += tv;
    __syncthreads();
  }
  if (tid < NB) bsum[tid] = sh[tid] - v;
}

__global__ __launch_bounds__(1024) void scan3_kernel(int* __restrict__ offsets,
                                                     const int* __restrict__ bsum,
                                                     int* __restrict__ cursor, int N, int N1) {
  int i = blockIdx.x * 1024 + threadIdx.x;
  if (i < N1) {
    int o = offsets[i] + bsum[blockIdx.x];
    offsets[i] = o;
    if (i < N) cursor[i] = o;
  }
}

// ---------- self-loop attention score (constant): leaky(ba1)@Wa2 + ba2 ----------
__global__ __launch_bounds__(64) void prep_kernel(const float* __restrict__ ba1,
                                                  const float* __restrict__ Wa2,
                                                  const float* __restrict__ ba2,
                                                  float* __restrict__ a_self) {
  int l = threadIdx.x;
  float t1 = ba1[l], t2 = ba1[l + 64];
  float v = LRELU(t1) * Wa2[l] + LRELU(t2) * Wa2[l + 64];
#pragma unroll
  for (int off = 32; off > 0; off >>= 1) v += __shfl_xor(v, off);
  if (l == 0) *a_self = v + ba2[0];
}

// ---------- CSR build: scatter rol values grouped by col ----------
__global__ void scatter_kernel(const int* __restrict__ rol, const int* __restrict__ col,
                               int* __restrict__ cursor, int* __restrict__ csr_rol, int E) {
  int e = blockIdx.x * blockDim.x + threadIdx.x;
  if (e < E) {
    int pos = atomicAdd(&cursor[col[e]], 1);
    csr_rol[pos] = rol[e];
  }
}

// ---------- fused flash-style node kernel: one wave per node, online softmax ----------
// embP row layout (u32 pairs): [0..63] = emb bf16x2, [64..127] = P bf16x2  (512 B/row)
__global__ __launch_bounds__(256) void fused_kernel(
    const int* __restrict__ offsets, const int* __restrict__ csr_rol,
    const unsigned* __restrict__ embP, const float2* __restrict__ ba1_2,
    const float2* __restrict__ Wa2_2, const float* __restrict__ ba2,
    const float* __restrict__ a_self_p, unsigned* __restrict__ msgb, int N, int nwt) {
  const int lane = threadIdx.x & 63;
  const int wid = blockIdx.x * (blockDim.x >> 6) + (threadIdx.x >> 6);
  const float2 b2 = ba1_2[lane];
  const float2 w2 = Wa2_2[lane];
  const float ba2v = *ba2;
  const float aself = *a_self_p;

#define LOGIT(pp) (LRELU(bflo(pp) - pcx + b2.x) * w2.x + LRELU(bfhi(pp) - pcy + b2.y) * w2.y)
#define ONLINE(aval, ue)                      \
  {                                           \
    float nm = fmaxf(m, (aval));              \
    float cc = __expf(m - nm);                \
    float w = __expf((aval)-nm);              \
    s = s * cc + w;                           \
    ax = ax * cc + w * bflo(ue);              \
    ay = ay * cc + w * bfhi(ue);              \
    m = nm;                                   \
  }

  for (int n = wid; n < N; n += nwt) {
    int j0 = offsets[n], j1 = offsets[n + 1];
    unsigned ue_own = embP[(size_t)n * 128 + lane];
    unsigned up_own = embP[(size_t)n * 128 + 64 + lane];
    float pcx = bflo(up_own), pcy = bfhi(up_own);
    float m = aself, s = 1.0f;
    float ax = bflo(ue_own), ay = bfhi(ue_own);
    int j = j0;
    for (; j + 4 <= j1; j += 4) {
      int r0 = csr_rol[j], r1 = csr_rol[j + 1], r2 = csr_rol[j + 2], r3 = csr_rol[j + 3];
      unsigned pe0 = embP[(size_t)r0 * 128 + lane];
      unsigned pp0 = embP[(size_t)r0 * 128 + 64 + lane];
      unsigned pe1 = embP[(size_t)r1 * 128 + lane];
      unsigned pp1 = embP[(size_t)r1 * 128 + 64 + lane];
      unsigned pe2 = embP[(size_t)r2 * 128 + lane];
      unsigned pp2 = embP[(size_t)r2 * 128 + 64 + lane];
      unsigned pe3 = embP[(size_t)r3 * 128 + lane];
      unsigned pp3 = embP[(size_t)r3 * 128 + 64 + lane];
      float v0 = LOGIT(pp0), v1 = LOGIT(pp1), v2 = LOGIT(pp2), v3 = LOGIT(pp3);
#pragma unroll
      for (int off = 32; off > 0; off >>= 1) {
        v0 += __shfl_xor(v0, off);
        v1 += __shfl_xor(v1, off);
        v2 += __shfl_xor(v2, off);
        v3 += __shfl_xor(v3, off);
      }
      ONLINE(v0 + ba2v, pe0);
      ONLINE(v1 + ba2v, pe1);
      ONLINE(v2 + ba2v, pe2);
      ONLINE(v3 + ba2v, pe3);
    }
    for (; j < j1; ++j) {
      int r = csr_rol[j];
      unsigned pe = embP[(size_t)r * 128 + lane];
      unsigned pp = embP[(size_t)r * 128 + 64 + lane];
      float v = LOGIT(pp);
#pragma unroll
      for (int off = 32; off > 0; off >>= 1) v += __shfl_xor(v, off);
      ONLINE(v + ba2v, pe);
    }
    float inv = 1.0f / (s + 1e-16f);
    msgb[(size_t)n * 64 + lane] =
        (unsigned)f2bf(ax * inv) | ((unsigned)f2bf(ay * inv) << 16);
  }
#undef LOGIT
#undef ONLINE
}

extern "C" void kernel_launch(void* const* d_in, const int* in_sizes, int n_in,
                              void* d_out, int out_size, void* d_ws, size_t ws_size,
                              hipStream_t stream) {
  const float* x     = (const float*)d_in[0];
  const int*   ei    = (const int*)d_in[1];
  const float* W_emb = (const float*)d_in[2];
  const float* b_emb = (const float*)d_in[3];
  const float* Wa1   = (const float*)d_in[4];
  const float* ba1   = (const float*)d_in[5];
  const float* Wa2   = (const float*)d_in[6];
  const float* ba2   = (const float*)d_in[7];
  const float* W_upd = (const float*)d_in[8];
  const float* b_upd = (const float*)d_in[9];
  float* out = (float*)d_out;

  const int N = in_sizes[0] / 128;
  const int E = in_sizes[1] / 2;
  const int* rol = ei;
  const int* col = ei + E;

  // workspace carve (all 256B aligned)
  char* base = (char*)d_ws;
  size_t off = 0;
  auto carve = [&](size_t bytes) {
    void* p = base + off;
    off = (off + bytes + 255) & ~(size_t)255;
    return p;
  };
  unsigned* embP   = (unsigned*)carve((size_t)N * 128 * 4);  // [emb|P] bf16 pairs, 512B/row
  unsigned* msgb   = (unsigned*)carve((size_t)N * 64 * 4);   // msg bf16 pairs, 256B/row
  unsigned short* WtA = (unsigned short*)carve(256 * 128 * 2);  // [W_emb|Wa1]^T bf16
  unsigned short* WtU = (unsigned short*)carve(128 * 128 * 2);  // W_upd^T bf16
  int*      csr_rol= (int*)carve((size_t)E * 4);
  float*    a_self = (float*)carve(16);
  int*      counts = (int*)carve((size_t)N * 4);
  int*      offsets= (int*)carve((size_t)(N + 1) * 4);
  int*      cursor = (int*)carve((size_t)N * 4);
  int*      bsum   = (int*)carve(128 * 4);
  (void)ws_size;

  const int N1 = N + 1;
  const int NB = (N1 + 1023) / 1024;  // 98 for N=100000 (must be <=128)
  const int SBLK = 2048;              // grid-stride blocks (8192 waves)
  const int NWT = SBLK * 4;

  zero_kernel<<<(N + 255) / 256, 256, 0, stream>>>(counts, N);
  wtrans_kernel<<<192, 256, 0, stream>>>(W_emb, Wa1, W_upd, WtA, WtU);

  // embP = bf16([x@W_emb + b_emb | x@Wa1]) via MFMA, A-frags straight from global f32
  gemm_embP_kernel<<<(N + 63) / 64, 256, 0, stream>>>(x, WtA, b_emb, (unsigned short*)embP, N);

  count_kernel<<<(E + 255) / 256, 256, 0, stream>>>(col, counts, E);
  scan1_kernel<<<NB, 1024, 0, stream>>>(counts, offsets, bsum, N, N1);
  scan2_kernel<<<1, 128, 0, stream>>>(bsum, NB);
  scan3_kernel<<<NB, 1024, 0, stream>>>(offsets, bsum, cursor, N, N1);
  prep_kernel<<<1, 64, 0, stream>>>(ba1, Wa2, ba2, a_self);
  scatter_kernel<<<(E + 255) / 256, 256, 0, stream>>>(rol, col, cursor, csr_rol, E);

  fused_kernel<<<SBLK, 256, 0, stream>>>(offsets, csr_rol, embP, (const float2*)ba1,
                                         (const float2*)Wa2, ba2, a_self, msgb, N, NWT);

  gemm_out_kernel<<<(N + 127) / 128, 256, 0, stream>>>((const unsigned short*)msgb, WtU, b_upd,
                                                       out, N);
}